// Round 2
// baseline (98.300 us; speedup 1.0000x reference)
//
#include <hip/hip_runtime.h>

// ParallelBellowsLayers: out[b,c] = relu( sum_e relu(x[b,c]*w1[c,e]+b1[c,e]) * w2[c,e] + b2[c] )
// B=128, C=40000, E=16. Output is flat (B, C) — identical indexing to x.
//
// R2: latency-bound fix. R1 had 628 blocks (2.45 waves/SIMD) and only 4
// outstanding loads/wave -> ~10 KB in flight per CU vs the ~22 KB Little's-law
// requirement for 6.3 TB/s. Now: 1256 blocks (~4.9 waves/SIMD) and a
// load-all/compute/store-all structure with 16 outstanding loads per wave.
// x/out use nontemporal (streaming) accesses so L2/L3 stay free for the
// 7.85 MB of per-channel params (re-read 8x, L3-served).

#define N_EXP    16
#define BATCH    128
#define C_DIM    40000
#define B_CHUNK  16
#define BLOCK    256

__global__ __launch_bounds__(BLOCK, 4)
void bellows_kernel(const float* __restrict__ x,
                    const float* __restrict__ w1,
                    const float* __restrict__ b1,
                    const float* __restrict__ w2,
                    const float* __restrict__ b2,
                    float* __restrict__ out)
{
    const int c = blockIdx.x * BLOCK + threadIdx.x;
    if (c >= C_DIM) return;
    const int b0 = blockIdx.y * B_CHUNK;

    // ---- per-channel params -> registers (rows are 64B, float4-aligned) ----
    const float4* w1v = (const float4*)(w1 + (size_t)c * N_EXP);
    const float4* b1v = (const float4*)(b1 + (size_t)c * N_EXP);
    const float4* w2v = (const float4*)(w2 + (size_t)c * N_EXP);
    float w1r[N_EXP], b1r[N_EXP], w2r[N_EXP];
    #pragma unroll
    for (int i = 0; i < N_EXP / 4; ++i) {
        float4 a = w1v[i], bq = b1v[i], w = w2v[i];
        w1r[4*i+0] = a.x;  w1r[4*i+1] = a.y;  w1r[4*i+2] = a.z;  w1r[4*i+3] = a.w;
        b1r[4*i+0] = bq.x; b1r[4*i+1] = bq.y; b1r[4*i+2] = bq.z; b1r[4*i+3] = bq.w;
        w2r[4*i+0] = w.x;  w2r[4*i+1] = w.y;  w2r[4*i+2] = w.z;  w2r[4*i+3] = w.w;
    }
    const float bias2 = b2[c];

    // ---- phase 1: issue all 16 x loads (16 outstanding per wave) ----
    const float* xp = x + (size_t)b0 * C_DIM + c;
    float xv[B_CHUNK];
    #pragma unroll
    for (int i = 0; i < B_CHUNK; ++i)
        xv[i] = __builtin_nontemporal_load(xp + (size_t)i * C_DIM);

    // ---- phase 2+3: compute and stream out ----
    float* op = out + (size_t)b0 * C_DIM + c;
    #pragma unroll
    for (int i = 0; i < B_CHUNK; ++i) {
        float acc0 = bias2, acc1 = 0.0f;
        #pragma unroll
        for (int e = 0; e < N_EXP; e += 2) {
            float h0 = fmaxf(fmaf(xv[i], w1r[e],   b1r[e]),   0.0f);
            float h1 = fmaxf(fmaf(xv[i], w1r[e+1], b1r[e+1]), 0.0f);
            acc0 = fmaf(h0, w2r[e],   acc0);
            acc1 = fmaf(h1, w2r[e+1], acc1);
        }
        __builtin_nontemporal_store(fmaxf(acc0 + acc1, 0.0f), op + (size_t)i * C_DIM);
    }
}

extern "C" void kernel_launch(void* const* d_in, const int* in_sizes, int n_in,
                              void* d_out, int out_size, void* d_ws, size_t ws_size,
                              hipStream_t stream) {
    const float* x  = (const float*)d_in[0];
    const float* w1 = (const float*)d_in[1];
    const float* b1 = (const float*)d_in[2];
    const float* w2 = (const float*)d_in[3];
    const float* b2 = (const float*)d_in[4];
    float* out = (float*)d_out;

    dim3 grid((C_DIM + BLOCK - 1) / BLOCK, BATCH / B_CHUNK);
    bellows_kernel<<<grid, dim3(BLOCK), 0, stream>>>(x, w1, b1, w2, b2, out);
}